// Round 1
// baseline (1279.330 us; speedup 1.0000x reference)
//
#include <hip/hip_runtime.h>

#define NN 100000
#define NE 1600000
#define NG 512
#define NC 16

static inline int cdiv(long long a, int b) { return (int)((a + b - 1) / b); }

__global__ void k_init_deg(float* deg, int n) {
  int i = blockIdx.x * blockDim.x + threadIdx.x;
  if (i < n) deg[i] = 1.0f;  // self loop
}

__global__ void k_deg_edges(const int* __restrict__ dst, float* deg, int ne) {
  int e = blockIdx.x * blockDim.x + threadIdx.x;
  if (e < ne) atomicAdd(&deg[dst[e]], 1.0f);
}

__global__ void k_dinv(float* deg, int n) {
  int i = blockIdx.x * blockDim.x + threadIdx.x;
  if (i < n) deg[i] = rsqrtf(deg[i]);  // deg >= 1 always
}

// out[i,f] = h[i,f] * dinv[i]^2   (self-loop contribution, also initializes out)
template <int F>
__global__ void k_agg_init(const float* __restrict__ h, const float* __restrict__ dinv,
                           float* __restrict__ out, int n) {
  int idx = blockIdx.x * blockDim.x + threadIdx.x;
  if (idx >= n * F) return;
  int i = idx / F;
  float di = dinv[i];
  out[idx] = h[idx] * di * di;
}

// out[dst,f] += h[src,f] * dinv[src]*dinv[dst]
template <int F>
__global__ void k_agg_edges(const float* __restrict__ h, const int* __restrict__ src,
                            const int* __restrict__ dst, const float* __restrict__ dinv,
                            float* __restrict__ out, int ne) {
  int idx = blockIdx.x * blockDim.x + threadIdx.x;
  if (idx >= ne * F) return;
  int e = idx / F;
  int f = idx - e * F;
  int s = src[e], d = dst[e];
  float w = dinv[s] * dinv[d];
  atomicAdd(&out[d * F + f], h[s * F + f] * w);
}

// out[i,o] = relu( sum_k a[i,k] * W[k,o] + b[o] )
template <int FIN, int FOUT>
__global__ void k_dense_relu(const float* __restrict__ a, const float* __restrict__ W,
                             const float* __restrict__ b, float* __restrict__ out, int n) {
  __shared__ float sW[FIN * FOUT];
  __shared__ float sb[FOUT];
  for (int t = threadIdx.x; t < FIN * FOUT; t += blockDim.x) sW[t] = W[t];
  for (int t = threadIdx.x; t < FOUT; t += blockDim.x) sb[t] = b[t];
  __syncthreads();
  int idx = blockIdx.x * blockDim.x + threadIdx.x;
  int i = idx / FOUT, o = idx % FOUT;
  if (i >= n) return;
  float acc = sb[o];
#pragma unroll
  for (int k = 0; k < FIN; ++k) acc += a[i * FIN + k] * sW[k * FOUT + o];
  out[idx] = fmaxf(acc, 0.0f);
}

__global__ void k_zero(float* p, int n) {
  int i = blockIdx.x * blockDim.x + threadIdx.x;
  if (i < n) p[i] = 0.0f;
}

__global__ void k_pool(const float* __restrict__ h, const int* __restrict__ batch,
                       float* __restrict__ gsum, float* __restrict__ gcnt, int n) {
  int idx = blockIdx.x * blockDim.x + threadIdx.x;
  if (idx >= n * 128) return;
  int i = idx >> 7, f = idx & 127;
  int g = batch[i];
  atomicAdd(&gsum[g * 128 + f], h[idx]);
  if (f == 0) atomicAdd(&gcnt[g], 1.0f);
}

// one wave per graph: logits = mean @ Wl + bl; log_softmax over 16 classes
__global__ void k_head(const float* __restrict__ gsum, const float* __restrict__ gcnt,
                       const float* __restrict__ Wl, const float* __restrict__ bl,
                       float* __restrict__ out) {
  int wave = threadIdx.x >> 6;
  int lane = threadIdx.x & 63;
  int g = blockIdx.x * 4 + wave;
  if (g >= NG) return;
  int c = lane & 15;     // class
  int part = lane >> 4;  // 0..3 (k-chunks)
  float inv = 1.0f / fmaxf(gcnt[g], 1.0f);
  float acc = 0.0f;
#pragma unroll
  for (int kk = 0; kk < 32; ++kk) {
    int k = part * 32 + kk;
    acc += gsum[g * 128 + k] * Wl[k * NC + c];
  }
  acc += __shfl_xor(acc, 16);
  acc += __shfl_xor(acc, 32);
  float logit = acc * inv + bl[c];
  float m = logit;
#pragma unroll
  for (int d = 1; d < 16; d <<= 1) m = fmaxf(m, __shfl_xor(m, d));
  float ex = expf(logit - m);
  float s = ex;
#pragma unroll
  for (int d = 1; d < 16; d <<= 1) s += __shfl_xor(s, d);
  if (lane < 16) out[g * NC + lane] = logit - m - logf(s);
}

extern "C" void kernel_launch(void* const* d_in, const int* in_sizes, int n_in,
                              void* d_out, int out_size, void* d_ws, size_t ws_size,
                              hipStream_t stream) {
  const float* x = (const float*)d_in[0];
  const int* ei = (const int*)d_in[1];
  const int* batch = (const int*)d_in[2];
  const float* W1 = (const float*)d_in[3];
  const float* b1 = (const float*)d_in[4];
  const float* W2 = (const float*)d_in[5];
  const float* b2 = (const float*)d_in[6];
  const float* W3 = (const float*)d_in[7];
  const float* b3 = (const float*)d_in[8];
  const float* Wl = (const float*)d_in[9];
  const float* bl = (const float*)d_in[10];
  const int* src = ei;
  const int* dst = ei + NE;

  float* dinv = (float*)d_ws;             // NN
  float* buf0 = dinv + 100352;            // NN*64 (agg buffer, max width 64)
  float* buf1 = buf0 + (size_t)NN * 64;   // NN*128 (dense output, max width 128)
  float* gsum = buf1 + (size_t)NN * 128;  // NG*128
  float* gcnt = gsum + NG * 128;          // NG

  const int B = 256;

  // degree / dinv (shared across layers)
  k_init_deg<<<cdiv(NN, B), B, 0, stream>>>(dinv, NN);
  k_deg_edges<<<cdiv(NE, B), B, 0, stream>>>(dst, dinv, NE);
  k_dinv<<<cdiv(NN, B), B, 0, stream>>>(dinv, NN);

  // layer 1: agg(x,13) -> dense 13->16
  k_agg_init<13><<<cdiv((long long)NN * 13, B), B, 0, stream>>>(x, dinv, buf0, NN);
  k_agg_edges<13><<<cdiv((long long)NE * 13, B), B, 0, stream>>>(x, src, dst, dinv, buf0, NE);
  k_dense_relu<13, 16><<<cdiv((long long)NN * 16, B), B, 0, stream>>>(buf0, W1, b1, buf1, NN);

  // layer 2: agg(h1,16) -> dense 16->64
  k_agg_init<16><<<cdiv((long long)NN * 16, B), B, 0, stream>>>(buf1, dinv, buf0, NN);
  k_agg_edges<16><<<cdiv((long long)NE * 16, B), B, 0, stream>>>(buf1, src, dst, dinv, buf0, NE);
  k_dense_relu<16, 64><<<cdiv((long long)NN * 64, B), B, 0, stream>>>(buf0, W2, b2, buf1, NN);

  // layer 3: agg(h2,64) -> dense 64->128
  k_agg_init<64><<<cdiv((long long)NN * 64, B), B, 0, stream>>>(buf1, dinv, buf0, NN);
  k_agg_edges<64><<<cdiv((long long)NE * 64, B), B, 0, stream>>>(buf1, src, dst, dinv, buf0, NE);
  k_dense_relu<64, 128><<<cdiv((long long)NN * 128, B), B, 0, stream>>>(buf0, W3, b3, buf1, NN);

  // pool + head
  k_zero<<<cdiv(NG * 128 + NG, B), B, 0, stream>>>(gsum, NG * 128 + NG);
  k_pool<<<cdiv((long long)NN * 128, B), B, 0, stream>>>(buf1, batch, gsum, gcnt, NN);
  k_head<<<NG / 4, B, 0, stream>>>(gsum, gcnt, Wl, bl, (float*)d_out);
}

// Round 2
// 627.881 us; speedup vs baseline: 2.0375x; 2.0375x over previous
//
#include <hip/hip_runtime.h>

#define NN 100000
#define NE 1600000
#define NG 512
#define NC 16

static inline int cdiv(long long a, int b) { return (int)((a + b - 1) / b); }

__global__ void k_zero_i(int* p, int n) {
  int i = blockIdx.x * blockDim.x + threadIdx.x;
  if (i < n) p[i] = 0;
}

// in-degree histogram (dst) + graph-size histogram (batch)
__global__ void k_hist(const int* __restrict__ dst, const int* __restrict__ batch,
                       int* __restrict__ count, int* __restrict__ gcnt) {
  int i = blockIdx.x * blockDim.x + threadIdx.x;
  if (i < NE) atomicAdd(&count[dst[i]], 1);
  if (i < NN) atomicAdd(&gcnt[batch[i]], 1);
}

__global__ void k_dinv(const int* __restrict__ count, float* __restrict__ dinv) {
  int i = blockIdx.x * blockDim.x + threadIdx.x;
  if (i < NN) dinv[i] = rsqrtf((float)(count[i] + 1));  // +1 self loop
}

// exclusive scan, 256/block; bsum gets block totals
__global__ void k_scan1(const int* __restrict__ in, int* __restrict__ out,
                        int* __restrict__ bsum, int n) {
  __shared__ int s[256];
  int t = threadIdx.x, i = blockIdx.x * 256 + t;
  int v = (i < n) ? in[i] : 0;
  s[t] = v;
  __syncthreads();
  for (int d = 1; d < 256; d <<= 1) {
    int a = (t >= d) ? s[t - d] : 0;
    __syncthreads();
    s[t] += a;
    __syncthreads();
  }
  if (i < n) out[i] = s[t] - v;  // exclusive
  if (t == 255) bsum[blockIdx.x] = s[255];
}

// single-block exclusive scan over <=512 values
__global__ void k_scan2(const int* __restrict__ in, int* __restrict__ out, int nb) {
  __shared__ int s[512];
  int t = threadIdx.x;
  int v = (t < nb) ? in[t] : 0;
  s[t] = v;
  __syncthreads();
  for (int d = 1; d < 512; d <<= 1) {
    int a = (t >= d) ? s[t - d] : 0;
    __syncthreads();
    s[t] += a;
    __syncthreads();
  }
  if (t < nb) out[t] = s[t] - v;
}

__global__ void k_scan3(int* __restrict__ out, const int* __restrict__ bpref, int n) {
  int i = blockIdx.x * blockDim.x + threadIdx.x;
  if (i < n) out[i] += bpref[i >> 8];
}

// scatter edges into CSR slots: csr[pos] = (src, weight-bits)
__global__ void k_fill(const int* __restrict__ src, const int* __restrict__ dst,
                       const int* __restrict__ offs, int* __restrict__ fill,
                       const float* __restrict__ dinv, int2* __restrict__ csr) {
  int e = blockIdx.x * blockDim.x + threadIdx.x;
  if (e >= NE) return;
  int s = src[e], d = dst[e];
  int pos = offs[d] + atomicAdd(&fill[d], 1);
  csr[pos] = make_int2(s, __float_as_int(dinv[s] * dinv[d]));
}

// gather-reduce aggregation. LPN = lanes per node (16 or 64).
template <int F, int LPN>
__global__ void k_agg(const float* __restrict__ h, const int2* __restrict__ csr,
                      const int* __restrict__ offs, const int* __restrict__ count,
                      const float* __restrict__ dinv, float* __restrict__ out) {
  int wave = threadIdx.x >> 6, lane = threadIdx.x & 63;
  const int NPW = 64 / LPN;  // nodes per wave
  int i = (blockIdx.x * 4 + wave) * NPW + ((LPN == 64) ? 0 : (lane >> 4));
  int f = lane & (LPN - 1);
  if (i >= NN) return;
  if (f >= F) return;
  int off = offs[i], cnt = count[i];
  float acc0 = 0.f, acc1 = 0.f;
  int j = 0;
  for (; j + 1 < cnt; j += 2) {
    int2 p0 = csr[off + j];
    int2 p1 = csr[off + j + 1];
    acc0 += h[(size_t)p0.x * F + f] * __int_as_float(p0.y);
    acc1 += h[(size_t)p1.x * F + f] * __int_as_float(p1.y);
  }
  if (j < cnt) {
    int2 p0 = csr[off + j];
    acc0 += h[(size_t)p0.x * F + f] * __int_as_float(p0.y);
  }
  float di = dinv[i];
  acc0 += h[(size_t)i * F + f] * di * di;  // self loop
  out[(size_t)i * F + f] = acc0 + acc1;
}

// out[i,o] = relu(sum_k a[i,k]*W[k,o] + b[o])
template <int FIN, int FOUT>
__global__ void k_dense_relu(const float* __restrict__ a, const float* __restrict__ W,
                             const float* __restrict__ b, float* __restrict__ out, int n) {
  __shared__ float sW[FIN * FOUT];
  __shared__ float sb[FOUT];
  for (int t = threadIdx.x; t < FIN * FOUT; t += blockDim.x) sW[t] = W[t];
  for (int t = threadIdx.x; t < FOUT; t += blockDim.x) sb[t] = b[t];
  __syncthreads();
  int idx = blockIdx.x * blockDim.x + threadIdx.x;
  int i = idx / FOUT, o = idx % FOUT;
  if (i >= n) return;
  float acc = sb[o];
#pragma unroll
  for (int k = 0; k < FIN; ++k) acc += a[(size_t)i * FIN + k] * sW[k * FOUT + o];
  out[idx] = fmaxf(acc, 0.0f);
}

// fused dense3(64->128)+relu+mean-pool: one block (128 thr) per graph
__global__ void k_dense3_pool(const float* __restrict__ a, const float* __restrict__ W3,
                              const float* __restrict__ b3, const int* __restrict__ gstart,
                              const int* __restrict__ gcnt, float* __restrict__ gmean) {
  __shared__ float sW[64 * 128];
  __shared__ float sa[64];
  int g = blockIdx.x, t = threadIdx.x;
  for (int k = t; k < 64 * 128; k += 128) sW[k] = W3[k];
  float bias = b3[t];
  __syncthreads();
  int s0 = gstart[g], c = gcnt[g];
  float pool = 0.f;
  for (int nidx = 0; nidx < c; ++nidx) {
    int node = s0 + nidx;
    if (t < 16) ((float4*)sa)[t] = ((const float4*)(a + (size_t)node * 64))[t];
    __syncthreads();
    float v = bias;
#pragma unroll
    for (int k = 0; k < 64; ++k) v += sa[k] * sW[k * 128 + t];
    pool += fmaxf(v, 0.f);
    __syncthreads();
  }
  gmean[g * 128 + t] = pool / (float)max(c, 1);
}

// one wave per graph: logits = gmean @ Wl + bl; log_softmax over 16 classes
__global__ void k_head(const float* __restrict__ gmean, const float* __restrict__ Wl,
                       const float* __restrict__ bl, float* __restrict__ out) {
  int wave = threadIdx.x >> 6, lane = threadIdx.x & 63;
  int g = blockIdx.x * 4 + wave;
  if (g >= NG) return;
  int c = lane & 15, part = lane >> 4;
  float acc = 0.f;
#pragma unroll
  for (int kk = 0; kk < 32; ++kk) {
    int k = part * 32 + kk;
    acc += gmean[g * 128 + k] * Wl[k * NC + c];
  }
  acc += __shfl_xor(acc, 16);
  acc += __shfl_xor(acc, 32);
  float logit = acc + bl[c];
  float m = logit;
#pragma unroll
  for (int d = 1; d < 16; d <<= 1) m = fmaxf(m, __shfl_xor(m, d));
  float ex = expf(logit - m), s = ex;
#pragma unroll
  for (int d = 1; d < 16; d <<= 1) s += __shfl_xor(s, d);
  if (lane < 16) out[g * NC + lane] = logit - m - logf(s);
}

extern "C" void kernel_launch(void* const* d_in, const int* in_sizes, int n_in,
                              void* d_out, int out_size, void* d_ws, size_t ws_size,
                              hipStream_t stream) {
  const float* x = (const float*)d_in[0];
  const int* ei = (const int*)d_in[1];
  const int* batch = (const int*)d_in[2];
  const float* W1 = (const float*)d_in[3];
  const float* b1 = (const float*)d_in[4];
  const float* W2 = (const float*)d_in[5];
  const float* b2 = (const float*)d_in[6];
  const float* W3 = (const float*)d_in[7];
  const float* b3 = (const float*)d_in[8];
  const float* Wl = (const float*)d_in[9];
  const float* bl = (const float*)d_in[10];
  const int* src = ei;
  const int* dst = ei + NE;

  // workspace layout (ints unless noted); total ~66 MB
  int* count = (int*)d_ws;       // NN
  int* fillc = count + NN;       // NN
  int* gcnt = fillc + NN;        // NG   (count..gcnt zeroed together)
  int* offs = gcnt + NG;         // NN
  int* gstart = offs + NN;       // NG
  int* bsum = gstart + NG;       // 1024
  int* bpref = bsum + 1024;      // 1024
  float* dinv = (float*)(bpref + 1024);         // NN
  int2* csr = (int2*)(dinv + NN);               // NE int2 (8B-aligned)
  float* bufA = (float*)(csr + NE);             // NN*64
  float* bufH = bufA + (size_t)NN * 64;         // NN*64
  float* gmean = bufH + (size_t)NN * 64;        // NG*128

  const int B = 256;
  const int NB_SCAN = cdiv(NN, 256);  // 391

  // CSR build + norms
  k_zero_i<<<cdiv(2 * NN + NG, B), B, 0, stream>>>(count, 2 * NN + NG);
  k_hist<<<cdiv(NE, B), B, 0, stream>>>(dst, batch, count, gcnt);
  k_dinv<<<cdiv(NN, B), B, 0, stream>>>(count, dinv);
  k_scan1<<<NB_SCAN, 256, 0, stream>>>(count, offs, bsum, NN);
  k_scan2<<<1, 512, 0, stream>>>(bsum, bpref, NB_SCAN);
  k_scan3<<<cdiv(NN, B), B, 0, stream>>>(offs, bpref, NN);
  k_scan2<<<1, 512, 0, stream>>>(gcnt, gstart, NG);
  k_fill<<<cdiv(NE, B), B, 0, stream>>>(src, dst, offs, fillc, dinv, csr);

  // layer 1: agg(x,13) -> dense 13->16
  k_agg<13, 16><<<cdiv(NN, 16), B, 0, stream>>>(x, csr, offs, count, dinv, bufA);
  k_dense_relu<13, 16><<<cdiv((long long)NN * 16, B), B, 0, stream>>>(bufA, W1, b1, bufH, NN);
  // layer 2: agg(h1,16) -> dense 16->64
  k_agg<16, 16><<<cdiv(NN, 16), B, 0, stream>>>(bufH, csr, offs, count, dinv, bufA);
  k_dense_relu<16, 64><<<cdiv((long long)NN * 64, B), B, 0, stream>>>(bufA, W2, b2, bufH, NN);
  // layer 3: agg(h2,64) -> fused dense(64->128)+relu+pool
  k_agg<64, 64><<<cdiv(NN, 4), B, 0, stream>>>(bufH, csr, offs, count, dinv, bufA);
  k_dense3_pool<<<NG, 128, 0, stream>>>(bufA, W3, b3, gstart, gcnt, gmean);

  // head
  k_head<<<NG / 4, B, 0, stream>>>(gmean, Wl, bl, (float*)d_out);
}

// Round 4
// 560.676 us; speedup vs baseline: 2.2818x; 1.1199x over previous
//
#include <hip/hip_runtime.h>

#define NN 100000
#define NE 1600000
#define NG 512
#define NC 16

static inline int cdiv(long long a, int b) { return (int)((a + b - 1) / b); }

__global__ void k_zero_i(int* p, int n) {
  int i = blockIdx.x * blockDim.x + threadIdx.x;
  if (i < n) p[i] = 0;
}

// in-degree histogram (dst) + graph-size histogram (batch)
__global__ void k_hist(const int* __restrict__ dst, const int* __restrict__ batch,
                       int* __restrict__ count, int* __restrict__ gcnt) {
  int i = blockIdx.x * blockDim.x + threadIdx.x;
  if (i < NE) atomicAdd(&count[dst[i]], 1);
  if (i < NN) atomicAdd(&gcnt[batch[i]], 1);
}

__global__ void k_dinv(const int* __restrict__ count, float* __restrict__ dinv) {
  int i = blockIdx.x * blockDim.x + threadIdx.x;
  if (i < NN) dinv[i] = rsqrtf((float)(count[i] + 1));  // +1 self loop
}

// exclusive scan, 256/block; bsum gets block totals
__global__ void k_scan1(const int* __restrict__ in, int* __restrict__ out,
                        int* __restrict__ bsum, int n) {
  __shared__ int s[256];
  int t = threadIdx.x, i = blockIdx.x * 256 + t;
  int v = (i < n) ? in[i] : 0;
  s[t] = v;
  __syncthreads();
  for (int d = 1; d < 256; d <<= 1) {
    int a = (t >= d) ? s[t - d] : 0;
    __syncthreads();
    s[t] += a;
    __syncthreads();
  }
  if (i < n) out[i] = s[t] - v;  // exclusive
  if (t == 255) bsum[blockIdx.x] = s[255];
}

// single-block exclusive scan over <=512 values
__global__ void k_scan2(const int* __restrict__ in, int* __restrict__ out, int nb) {
  __shared__ int s[512];
  int t = threadIdx.x;
  int v = (t < nb) ? in[t] : 0;
  s[t] = v;
  __syncthreads();
  for (int d = 1; d < 512; d <<= 1) {
    int a = (t >= d) ? s[t - d] : 0;
    __syncthreads();
    s[t] += a;
    __syncthreads();
  }
  if (t < nb) out[t] = s[t] - v;
}

__global__ void k_scan3(int* __restrict__ out, const int* __restrict__ bpref, int n) {
  int i = blockIdx.x * blockDim.x + threadIdx.x;
  if (i < n) out[i] += bpref[i >> 8];
}

// scatter edges into CSR slots: csr[pos] = (src, weight-bits)
__global__ void k_fill(const int* __restrict__ src, const int* __restrict__ dst,
                       const int* __restrict__ offs, int* __restrict__ fill,
                       const float* __restrict__ dinv, int2* __restrict__ csr) {
  int e = blockIdx.x * blockDim.x + threadIdx.x;
  if (e >= NE) return;
  int s = src[e], d = dst[e];
  int pos = offs[d] + atomicAdd(&fill[d], 1);
  csr[pos] = make_int2(s, __float_as_int(dinv[s] * dinv[d]));
}

// gather-reduce aggregation. LPN = lanes per node (16 or 64).
template <int F, int LPN>
__global__ void k_agg(const float* __restrict__ h, const int2* __restrict__ csr,
                      const int* __restrict__ offs, const int* __restrict__ count,
                      const float* __restrict__ dinv, float* __restrict__ out) {
  int wave = threadIdx.x >> 6, lane = threadIdx.x & 63;
  const int NPW = 64 / LPN;  // nodes per wave
  int i = (blockIdx.x * 4 + wave) * NPW + ((LPN == 64) ? 0 : (lane >> 4));
  int f = lane & (LPN - 1);
  if (i >= NN) return;
  if (f >= F) return;
  int off = offs[i], cnt = count[i];
  float acc0 = 0.f, acc1 = 0.f, acc2 = 0.f, acc3 = 0.f;
  int j = 0;
  for (; j + 3 < cnt; j += 4) {
    int2 p0 = csr[off + j];
    int2 p1 = csr[off + j + 1];
    int2 p2 = csr[off + j + 2];
    int2 p3 = csr[off + j + 3];
    acc0 += h[(size_t)p0.x * F + f] * __int_as_float(p0.y);
    acc1 += h[(size_t)p1.x * F + f] * __int_as_float(p1.y);
    acc2 += h[(size_t)p2.x * F + f] * __int_as_float(p2.y);
    acc3 += h[(size_t)p3.x * F + f] * __int_as_float(p3.y);
  }
  for (; j < cnt; ++j) {
    int2 p0 = csr[off + j];
    acc0 += h[(size_t)p0.x * F + f] * __int_as_float(p0.y);
  }
  float di = dinv[i];
  acc0 += h[(size_t)i * F + f] * di * di;  // self loop
  out[(size_t)i * F + f] = (acc0 + acc1) + (acc2 + acc3);
}

// out[i,o] = relu(sum_k a[i,k]*W[k,o] + b[o])
template <int FIN, int FOUT>
__global__ void k_dense_relu(const float* __restrict__ a, const float* __restrict__ W,
                             const float* __restrict__ b, float* __restrict__ out, int n) {
  __shared__ float sW[FIN * FOUT];
  __shared__ float sb[FOUT];
  for (int t = threadIdx.x; t < FIN * FOUT; t += blockDim.x) sW[t] = W[t];
  for (int t = threadIdx.x; t < FOUT; t += blockDim.x) sb[t] = b[t];
  __syncthreads();
  int idx = blockIdx.x * blockDim.x + threadIdx.x;
  int i = idx / FOUT, o = idx % FOUT;
  if (i >= n) return;
  float acc = sb[o];
#pragma unroll
  for (int k = 0; k < FIN; ++k) acc += a[(size_t)i * FIN + k] * sW[k * FOUT + o];
  out[idx] = fmaxf(acc, 0.0f);
}

// fused dense3(64->128)+relu+segmented mean-pool over sorted batch.
// 256 threads = 2 node-streams x 128 features; 64 nodes per block.
#define D3N 64
__global__ void k_dense3_pool2(const float* __restrict__ a, const float* __restrict__ W3,
                               const float* __restrict__ b3, const int* __restrict__ batch,
                               float* __restrict__ gsum) {
  __shared__ float sW[64 * 128];
  __shared__ float sa[2][64];
  int t = threadIdx.x;
  int half = t >> 7;  // node-stream 0/1
  int o = t & 127;    // output feature
  for (int k = t; k < 64 * 128; k += 256) sW[k] = W3[k];
  float bias = b3[o];
  int n0 = blockIdx.x * D3N;
  float acc = 0.f;
  int curg = -1;
#pragma unroll 1
  for (int it = 0; it < D3N / 2; ++it) {
    int n = n0 + it * 2 + half;
    bool valid = n < NN;
    __syncthreads();
    if (valid && o < 16)
      ((float4*)sa[half])[o] = ((const float4*)(a + (size_t)n * 64))[o];
    __syncthreads();
    if (valid) {
      float v = bias;
#pragma unroll
      for (int k = 0; k < 64; ++k) v += sa[half][k] * sW[k * 128 + o];
      int g = batch[n];
      if (g != curg) {
        if (curg >= 0) atomicAdd(&gsum[curg * 128 + o], acc);
        curg = g;
        acc = 0.f;
      }
      acc += fmaxf(v, 0.f);
    }
  }
  if (curg >= 0) atomicAdd(&gsum[curg * 128 + o], acc);
}

// one wave per graph: logits = (gsum/cnt) @ Wl + bl; log_softmax over 16 classes
__global__ void k_head(const float* __restrict__ gsum, const int* __restrict__ gcnt,
                       const float* __restrict__ Wl, const float* __restrict__ bl,
                       float* __restrict__ out) {
  int wave = threadIdx.x >> 6, lane = threadIdx.x & 63;
  int g = blockIdx.x * 4 + wave;
  if (g >= NG) return;
  int c = lane & 15, part = lane >> 4;
  float acc = 0.f;
#pragma unroll
  for (int kk = 0; kk < 32; ++kk) {
    int k = part * 32 + kk;
    acc += gsum[g * 128 + k] * Wl[k * NC + c];
  }
  acc += __shfl_xor(acc, 16);
  acc += __shfl_xor(acc, 32);
  float inv = 1.0f / (float)max(gcnt[g], 1);
  float logit = acc * inv + bl[c];
  float m = logit;
#pragma unroll
  for (int d = 1; d < 16; d <<= 1) m = fmaxf(m, __shfl_xor(m, d));
  float ex = expf(logit - m), s = ex;
#pragma unroll
  for (int d = 1; d < 16; d <<= 1) s += __shfl_xor(s, d);
  if (lane < 16) out[g * NC + lane] = logit - m - logf(s);
}

extern "C" void kernel_launch(void* const* d_in, const int* in_sizes, int n_in,
                              void* d_out, int out_size, void* d_ws, size_t ws_size,
                              hipStream_t stream) {
  const float* x = (const float*)d_in[0];
  const int* ei = (const int*)d_in[1];
  const int* batch = (const int*)d_in[2];
  const float* W1 = (const float*)d_in[3];
  const float* b1 = (const float*)d_in[4];
  const float* W2 = (const float*)d_in[5];
  const float* b2 = (const float*)d_in[6];
  const float* W3 = (const float*)d_in[7];
  const float* b3 = (const float*)d_in[8];
  const float* Wl = (const float*)d_in[9];
  const float* bl = (const float*)d_in[10];
  const int* src = ei;
  const int* dst = ei + NE;

  // workspace layout
  int* count = (int*)d_ws;                 // NN
  int* fillc = count + NN;                 // NN
  int* gcnt = fillc + NN;                  // NG
  float* gsum = (float*)(gcnt + NG);       // NG*128  (zeroed with the ints)
  int* offs = (int*)(gsum + NG * 128);     // NN
  int* bsum = offs + NN;                   // 1024
  int* bpref = bsum + 1024;                // 1024
  float* dinv = (float*)(bpref + 1024);    // NN
  int2* csr = (int2*)(dinv + NN);          // NE int2
  float* bufA = (float*)(csr + NE);        // NN*64
  float* bufH = bufA + (size_t)NN * 64;    // NN*64

  const int B = 256;
  const int NB_SCAN = cdiv(NN, 256);  // 391
  const int n_zero_elems = 2 * NN + NG + NG * 128;

  // CSR build + norms (+ zero gsum)
  k_zero_i<<<cdiv(n_zero_elems, B), B, 0, stream>>>(count, n_zero_elems);
  k_hist<<<cdiv(NE, B), B, 0, stream>>>(dst, batch, count, gcnt);
  k_dinv<<<cdiv(NN, B), B, 0, stream>>>(count, dinv);
  k_scan1<<<NB_SCAN, 256, 0, stream>>>(count, offs, bsum, NN);
  k_scan2<<<1, 512, 0, stream>>>(bsum, bpref, NB_SCAN);
  k_scan3<<<cdiv(NN, B), B, 0, stream>>>(offs, bpref, NN);
  k_fill<<<cdiv(NE, B), B, 0, stream>>>(src, dst, offs, fillc, dinv, csr);

  // layer 1: agg(x,13) -> dense 13->16
  k_agg<13, 16><<<cdiv(NN, 16), B, 0, stream>>>(x, csr, offs, count, dinv, bufA);
  k_dense_relu<13, 16><<<cdiv((long long)NN * 16, B), B, 0, stream>>>(bufA, W1, b1, bufH, NN);
  // layer 2: agg(h1,16) -> dense 16->64
  k_agg<16, 16><<<cdiv(NN, 16), B, 0, stream>>>(bufH, csr, offs, count, dinv, bufA);
  k_dense_relu<16, 64><<<cdiv((long long)NN * 64, B), B, 0, stream>>>(bufA, W2, b2, bufH, NN);
  // layer 3: agg(h2,64) -> fused dense(64->128)+relu+pool
  k_agg<64, 64><<<cdiv(NN, 4), B, 0, stream>>>(bufH, csr, offs, count, dinv, bufA);
  k_dense3_pool2<<<cdiv(NN, D3N), 256, 0, stream>>>(bufA, W3, b3, batch, gsum);

  // head
  k_head<<<NG / 4, B, 0, stream>>>(gsum, gcnt, Wl, bl, (float*)d_out);
}

// Round 5
// 472.727 us; speedup vs baseline: 2.7063x; 1.1860x over previous
//
#include <hip/hip_runtime.h>

#define NN 100000
#define NE 1600000
#define NG 512
#define NC 16

static inline int cdiv(long long a, int b) { return (int)((a + b - 1) / b); }

__global__ void k_zero_i(int* p, int n) {
  int i = blockIdx.x * blockDim.x + threadIdx.x;
  if (i < n) p[i] = 0;
}

// in-degree histogram (dst) + graph-size histogram (batch)
__global__ void k_hist(const int* __restrict__ dst, const int* __restrict__ batch,
                       int* __restrict__ count, int* __restrict__ gcnt) {
  int i = blockIdx.x * blockDim.x + threadIdx.x;
  if (i < NE) atomicAdd(&count[dst[i]], 1);
  if (i < NN) atomicAdd(&gcnt[batch[i]], 1);
}

__global__ void k_dinv(const int* __restrict__ count, float* __restrict__ dinv) {
  int i = blockIdx.x * blockDim.x + threadIdx.x;
  if (i < NN) dinv[i] = rsqrtf((float)(count[i] + 1));  // +1 self loop
}

// exclusive scan, 256/block; bsum gets block totals
__global__ void k_scan1(const int* __restrict__ in, int* __restrict__ out,
                        int* __restrict__ bsum, int n) {
  __shared__ int s[256];
  int t = threadIdx.x, i = blockIdx.x * 256 + t;
  int v = (i < n) ? in[i] : 0;
  s[t] = v;
  __syncthreads();
  for (int d = 1; d < 256; d <<= 1) {
    int a = (t >= d) ? s[t - d] : 0;
    __syncthreads();
    s[t] += a;
    __syncthreads();
  }
  if (i < n) out[i] = s[t] - v;  // exclusive
  if (t == 255) bsum[blockIdx.x] = s[255];
}

// single-block exclusive scan over <=512 values
__global__ void k_scan2(const int* __restrict__ in, int* __restrict__ out, int nb) {
  __shared__ int s[512];
  int t = threadIdx.x;
  int v = (t < nb) ? in[t] : 0;
  s[t] = v;
  __syncthreads();
  for (int d = 1; d < 512; d <<= 1) {
    int a = (t >= d) ? s[t - d] : 0;
    __syncthreads();
    s[t] += a;
    __syncthreads();
  }
  if (t < nb) out[t] = s[t] - v;
}

__global__ void k_scan3(int* __restrict__ out, const int* __restrict__ bpref, int n) {
  int i = blockIdx.x * blockDim.x + threadIdx.x;
  if (i < n) out[i] += bpref[i >> 8];
}

// scatter edges into CSR slots: csr[pos] = (src, weight-bits)
__global__ void k_fill(const int* __restrict__ src, const int* __restrict__ dst,
                       const int* __restrict__ offs, int* __restrict__ fill,
                       const float* __restrict__ dinv, int2* __restrict__ csr) {
  int e = blockIdx.x * blockDim.x + threadIdx.x;
  if (e >= NE) return;
  int s = src[e], d = dst[e];
  int pos = offs[d] + atomicAdd(&fill[d], 1);
  csr[pos] = make_int2(s, __float_as_int(dinv[s] * dinv[d]));
}

// gather-reduce aggregation. LPN = lanes per node (16 or 64).
template <int F, int LPN>
__global__ void k_agg(const float* __restrict__ h, const int2* __restrict__ csr,
                      const int* __restrict__ offs, const int* __restrict__ count,
                      const float* __restrict__ dinv, float* __restrict__ out) {
  int wave = threadIdx.x >> 6, lane = threadIdx.x & 63;
  const int NPW = 64 / LPN;  // nodes per wave
  int i = (blockIdx.x * 4 + wave) * NPW + ((LPN == 64) ? 0 : (lane >> 4));
  int f = lane & (LPN - 1);
  if (i >= NN) return;
  if (f >= F) return;
  int off = offs[i], cnt = count[i];
  float acc0 = 0.f, acc1 = 0.f, acc2 = 0.f, acc3 = 0.f;
  int j = 0;
  for (; j + 3 < cnt; j += 4) {
    int2 p0 = csr[off + j];
    int2 p1 = csr[off + j + 1];
    int2 p2 = csr[off + j + 2];
    int2 p3 = csr[off + j + 3];
    acc0 += h[(size_t)p0.x * F + f] * __int_as_float(p0.y);
    acc1 += h[(size_t)p1.x * F + f] * __int_as_float(p1.y);
    acc2 += h[(size_t)p2.x * F + f] * __int_as_float(p2.y);
    acc3 += h[(size_t)p3.x * F + f] * __int_as_float(p3.y);
  }
  for (; j < cnt; ++j) {
    int2 p0 = csr[off + j];
    acc0 += h[(size_t)p0.x * F + f] * __int_as_float(p0.y);
  }
  float di = dinv[i];
  acc0 += h[(size_t)i * F + f] * di * di;  // self loop
  out[(size_t)i * F + f] = (acc0 + acc1) + (acc2 + acc3);
}

// out[i,o] = relu(sum_k a[i,k]*W[k,o] + b[o])
template <int FIN, int FOUT>
__global__ void k_dense_relu(const float* __restrict__ a, const float* __restrict__ W,
                             const float* __restrict__ b, float* __restrict__ out, int n) {
  __shared__ float sW[FIN * FOUT];
  __shared__ float sb[FOUT];
  for (int t = threadIdx.x; t < FIN * FOUT; t += blockDim.x) sW[t] = W[t];
  for (int t = threadIdx.x; t < FOUT; t += blockDim.x) sb[t] = b[t];
  __syncthreads();
  int idx = blockIdx.x * blockDim.x + threadIdx.x;
  int i = idx / FOUT, o = idx % FOUT;
  if (i >= n) return;
  float acc = sb[o];
#pragma unroll
  for (int k = 0; k < FIN; ++k) acc += a[(size_t)i * FIN + k] * sW[k * FOUT + o];
  out[idx] = fmaxf(acc, 0.0f);
}

// fused dense3(64->128)+relu+segmented mean-pool over sorted batch.
// W3 column in 64 VGPRs/thread; a-rows staged in LDS, read as uniform float4.
#define D3_NPB 128  // nodes per block
#define D3_CH 32    // nodes per staged chunk
__global__ void k_dense3_pool3(const float* __restrict__ a, const float* __restrict__ W3,
                               const float* __restrict__ b3, const int* __restrict__ batch,
                               float* __restrict__ gsum) {
  __shared__ float sa[D3_CH * 64];
  int t = threadIdx.x;
  int half = t >> 7, o = t & 127;
  float wcol[64];
#pragma unroll
  for (int k = 0; k < 64; ++k) wcol[k] = W3[k * 128 + o];
  float bias = b3[o];
  int base = blockIdx.x * D3_NPB;
  float acc = 0.f;
  int curg = -1;
#pragma unroll 1
  for (int c0 = 0; c0 < D3_NPB; c0 += D3_CH) {
    __syncthreads();
    // stage D3_CH node rows (zero-fill OOB); 512 float4 by 256 threads
#pragma unroll
    for (int r = 0; r < (D3_CH * 16) / 256; ++r) {
      int idx = r * 256 + t;  // float4 index within chunk
      int node = base + c0 + (idx >> 4);
      float4 v = make_float4(0.f, 0.f, 0.f, 0.f);
      if (node < NN) v = ((const float4*)(a + (size_t)node * 64))[idx & 15];
      ((float4*)sa)[idx] = v;
    }
    __syncthreads();
#pragma unroll 1
    for (int j = 0; j < D3_CH / 2; ++j) {
      int local = half * (D3_CH / 2) + j;
      int n = base + c0 + local;
      if (n >= NN) break;
      const float* row = sa + local * 64;
      float v = bias;
#pragma unroll
      for (int q = 0; q < 16; ++q) {
        float4 av = ((const float4*)row)[q];
        v += av.x * wcol[4 * q] + av.y * wcol[4 * q + 1] + av.z * wcol[4 * q + 2] +
             av.w * wcol[4 * q + 3];
      }
      int g = batch[n];
      if (g != curg) {
        if (curg >= 0) atomicAdd(&gsum[curg * 128 + o], acc);
        curg = g;
        acc = 0.f;
      }
      acc += fmaxf(v, 0.f);
    }
  }
  if (curg >= 0) atomicAdd(&gsum[curg * 128 + o], acc);
}

// one wave per graph: logits = (gsum/cnt) @ Wl + bl; log_softmax over 16 classes
__global__ void k_head(const float* __restrict__ gsum, const int* __restrict__ gcnt,
                       const float* __restrict__ Wl, const float* __restrict__ bl,
                       float* __restrict__ out) {
  int wave = threadIdx.x >> 6, lane = threadIdx.x & 63;
  int g = blockIdx.x * 4 + wave;
  if (g >= NG) return;
  int c = lane & 15, part = lane >> 4;
  float acc = 0.f;
#pragma unroll
  for (int kk = 0; kk < 32; ++kk) {
    int k = part * 32 + kk;
    acc += gsum[g * 128 + k] * Wl[k * NC + c];
  }
  acc += __shfl_xor(acc, 16);
  acc += __shfl_xor(acc, 32);
  float inv = 1.0f / (float)max(gcnt[g], 1);
  float logit = acc * inv + bl[c];
  float m = logit;
#pragma unroll
  for (int d = 1; d < 16; d <<= 1) m = fmaxf(m, __shfl_xor(m, d));
  float ex = expf(logit - m), s = ex;
#pragma unroll
  for (int d = 1; d < 16; d <<= 1) s += __shfl_xor(s, d);
  if (lane < 16) out[g * NC + lane] = logit - m - logf(s);
}

extern "C" void kernel_launch(void* const* d_in, const int* in_sizes, int n_in,
                              void* d_out, int out_size, void* d_ws, size_t ws_size,
                              hipStream_t stream) {
  const float* x = (const float*)d_in[0];
  const int* ei = (const int*)d_in[1];
  const int* batch = (const int*)d_in[2];
  const float* W1 = (const float*)d_in[3];
  const float* b1 = (const float*)d_in[4];
  const float* W2 = (const float*)d_in[5];
  const float* b2 = (const float*)d_in[6];
  const float* W3 = (const float*)d_in[7];
  const float* b3 = (const float*)d_in[8];
  const float* Wl = (const float*)d_in[9];
  const float* bl = (const float*)d_in[10];
  const int* src = ei;
  const int* dst = ei + NE;

  // workspace layout
  int* count = (int*)d_ws;                 // NN
  int* fillc = count + NN;                 // NN
  int* gcnt = fillc + NN;                  // NG
  float* gsum = (float*)(gcnt + NG);       // NG*128  (zeroed with the ints)
  int* offs = (int*)(gsum + NG * 128);     // NN
  int* bsum = offs + NN;                   // 1024
  int* bpref = bsum + 1024;                // 1024
  float* dinv = (float*)(bpref + 1024);    // NN
  int2* csr = (int2*)(dinv + NN);          // NE int2
  float* bufA = (float*)(csr + NE);        // NN*64
  float* bufH = bufA + (size_t)NN * 64;    // NN*64

  const int B = 256;
  const int NB_SCAN = cdiv(NN, 256);  // 391
  const int n_zero_elems = 2 * NN + NG + NG * 128;

  // CSR build + norms (+ zero gsum)
  k_zero_i<<<cdiv(n_zero_elems, B), B, 0, stream>>>(count, n_zero_elems);
  k_hist<<<cdiv(NE, B), B, 0, stream>>>(dst, batch, count, gcnt);
  k_dinv<<<cdiv(NN, B), B, 0, stream>>>(count, dinv);
  k_scan1<<<NB_SCAN, 256, 0, stream>>>(count, offs, bsum, NN);
  k_scan2<<<1, 512, 0, stream>>>(bsum, bpref, NB_SCAN);
  k_scan3<<<cdiv(NN, B), B, 0, stream>>>(offs, bpref, NN);
  k_fill<<<cdiv(NE, B), B, 0, stream>>>(src, dst, offs, fillc, dinv, csr);

  // layer 1: agg(x,13) -> dense 13->16
  k_agg<13, 16><<<cdiv(NN, 16), B, 0, stream>>>(x, csr, offs, count, dinv, bufA);
  k_dense_relu<13, 16><<<cdiv((long long)NN * 16, B), B, 0, stream>>>(bufA, W1, b1, bufH, NN);
  // layer 2: agg(h1,16) -> dense 16->64
  k_agg<16, 16><<<cdiv(NN, 16), B, 0, stream>>>(bufH, csr, offs, count, dinv, bufA);
  k_dense_relu<16, 64><<<cdiv((long long)NN * 64, B), B, 0, stream>>>(bufA, W2, b2, bufH, NN);
  // layer 3: agg(h2,64) -> fused dense(64->128)+relu+pool
  k_agg<64, 64><<<cdiv(NN, 4), B, 0, stream>>>(bufH, csr, offs, count, dinv, bufA);
  k_dense3_pool3<<<cdiv(NN, D3_NPB), 256, 0, stream>>>(bufA, W3, b3, batch, gsum);

  // head
  k_head<<<NG / 4, B, 0, stream>>>(gsum, gcnt, Wl, bl, (float*)d_out);
}

// Round 6
// 421.022 us; speedup vs baseline: 3.0386x; 1.1228x over previous
//
#include <hip/hip_runtime.h>

#define NN 100000
#define NE 1600000
#define NG 512
#define NC 16
#define HC 8  // histogram copies

static inline int cdiv(long long a, int b) { return (int)((a + b - 1) / b); }

__global__ void k_zero_i(int* p, int n) {
  int i = blockIdx.x * blockDim.x + threadIdx.x;
  if (i < n) p[i] = 0;
}

// 8-way replicated in-degree histogram: cnt[d*HC + (e&7)]
__global__ void k_hist8(const int* __restrict__ dst, int* __restrict__ cnt) {
  int e = blockIdx.x * blockDim.x + threadIdx.x;
  if (e < NE) atomicAdd(&cnt[dst[e] * HC + (e & (HC - 1))], 1);
}

// sum copies -> count; copies -> per-copy exclusive prefix (in place); dinv
__global__ void k_reduce(int* __restrict__ cnt, int* __restrict__ count,
                         float* __restrict__ dinv) {
  int i = blockIdx.x * blockDim.x + threadIdx.x;
  if (i >= NN) return;
  int s = 0;
#pragma unroll
  for (int c = 0; c < HC; ++c) {
    int v = cnt[i * HC + c];
    cnt[i * HC + c] = s;
    s += v;
  }
  count[i] = s;
  dinv[i] = rsqrtf((float)(s + 1));  // +1 self loop
}

// graph boundaries from sorted batch: gstart[g] = first node index with batch >= g
__global__ void k_bounds(const int* __restrict__ batch, int* __restrict__ gstart) {
  int i = blockIdx.x * blockDim.x + threadIdx.x;
  if (i > NN) return;
  int b = (i < NN) ? batch[i] : NG;
  int bp = (i > 0) ? batch[i - 1] : -1;
  for (int g = bp + 1; g <= b; ++g) gstart[g] = i;
}

// exclusive scan, 256/block; bsum gets block totals
__global__ void k_scan1(const int* __restrict__ in, int* __restrict__ out,
                        int* __restrict__ bsum, int n) {
  __shared__ int s[256];
  int t = threadIdx.x, i = blockIdx.x * 256 + t;
  int v = (i < n) ? in[i] : 0;
  s[t] = v;
  __syncthreads();
  for (int d = 1; d < 256; d <<= 1) {
    int a = (t >= d) ? s[t - d] : 0;
    __syncthreads();
    s[t] += a;
    __syncthreads();
  }
  if (i < n) out[i] = s[t] - v;  // exclusive
  if (t == 255) bsum[blockIdx.x] = s[255];
}

// single-block exclusive scan over <=512 values
__global__ void k_scan2(const int* __restrict__ in, int* __restrict__ out, int nb) {
  __shared__ int s[512];
  int t = threadIdx.x;
  int v = (t < nb) ? in[t] : 0;
  s[t] = v;
  __syncthreads();
  for (int d = 1; d < 512; d <<= 1) {
    int a = (t >= d) ? s[t - d] : 0;
    __syncthreads();
    s[t] += a;
    __syncthreads();
  }
  if (t < nb) out[t] = s[t] - v;
}

__global__ void k_scan3(int* __restrict__ out, const int* __restrict__ bpref, int n) {
  int i = blockIdx.x * blockDim.x + threadIdx.x;
  if (i < n) out[i] += bpref[i >> 8];
}

// scatter edges into CSR slots using per-copy prefixes (8x less atomic contention)
__global__ void k_fill(const int* __restrict__ src, const int* __restrict__ dst,
                       const int* __restrict__ offs, const int* __restrict__ cnt,
                       int* __restrict__ fillc, const float* __restrict__ dinv,
                       int2* __restrict__ csr) {
  int e = blockIdx.x * blockDim.x + threadIdx.x;
  if (e >= NE) return;
  int s = src[e], d = dst[e];
  int c = e & (HC - 1);
  int pos = offs[d] + cnt[d * HC + c] + atomicAdd(&fillc[d * HC + c], 1);
  csr[pos] = make_int2(s, __float_as_int(dinv[s] * dinv[d]));
}

// gather-reduce aggregation. LPN = lanes per node (16 or 64).
template <int F, int LPN>
__global__ void k_agg(const float* __restrict__ h, const int2* __restrict__ csr,
                      const int* __restrict__ offs, const int* __restrict__ count,
                      const float* __restrict__ dinv, float* __restrict__ out) {
  int wave = threadIdx.x >> 6, lane = threadIdx.x & 63;
  const int NPW = 64 / LPN;  // nodes per wave
  int i = (blockIdx.x * 4 + wave) * NPW + ((LPN == 64) ? 0 : (lane >> 4));
  int f = lane & (LPN - 1);
  if (i >= NN) return;
  if (f >= F) return;
  int off = offs[i], cnt = count[i];
  float acc0 = 0.f, acc1 = 0.f, acc2 = 0.f, acc3 = 0.f;
  int j = 0;
  for (; j + 3 < cnt; j += 4) {
    int2 p0 = csr[off + j];
    int2 p1 = csr[off + j + 1];
    int2 p2 = csr[off + j + 2];
    int2 p3 = csr[off + j + 3];
    acc0 += h[(size_t)p0.x * F + f] * __int_as_float(p0.y);
    acc1 += h[(size_t)p1.x * F + f] * __int_as_float(p1.y);
    acc2 += h[(size_t)p2.x * F + f] * __int_as_float(p2.y);
    acc3 += h[(size_t)p3.x * F + f] * __int_as_float(p3.y);
  }
  for (; j < cnt; ++j) {
    int2 p0 = csr[off + j];
    acc0 += h[(size_t)p0.x * F + f] * __int_as_float(p0.y);
  }
  float di = dinv[i];
  acc0 += h[(size_t)i * F + f] * di * di;  // self loop
  out[(size_t)i * F + f] = (acc0 + acc1) + (acc2 + acc3);
}

// out[i,o] = relu(sum_k a[i,k]*W[k,o] + b[o])
template <int FIN, int FOUT>
__global__ void k_dense_relu(const float* __restrict__ a, const float* __restrict__ W,
                             const float* __restrict__ b, float* __restrict__ out, int n) {
  __shared__ float sW[FIN * FOUT];
  __shared__ float sb[FOUT];
  for (int t = threadIdx.x; t < FIN * FOUT; t += blockDim.x) sW[t] = W[t];
  for (int t = threadIdx.x; t < FOUT; t += blockDim.x) sb[t] = b[t];
  __syncthreads();
  int idx = blockIdx.x * blockDim.x + threadIdx.x;
  int i = idx / FOUT, o = idx % FOUT;
  if (i >= n) return;
  float acc = sb[o];
#pragma unroll
  for (int k = 0; k < FIN; ++k) acc += a[(size_t)i * FIN + k] * sW[k * FOUT + o];
  out[idx] = fmaxf(acc, 0.0f);
}

// fused dense3(64->128)+relu+segmented mean-pool over sorted batch.
// W3 column in 64 VGPRs/thread; a-rows staged in LDS, read as uniform float4.
#define D3_NPB 128  // nodes per block
#define D3_CH 32    // nodes per staged chunk
__global__ void k_dense3_pool3(const float* __restrict__ a, const float* __restrict__ W3,
                               const float* __restrict__ b3, const int* __restrict__ batch,
                               float* __restrict__ gsum) {
  __shared__ float sa[D3_CH * 64];
  int t = threadIdx.x;
  int half = t >> 7, o = t & 127;
  float wcol[64];
#pragma unroll
  for (int k = 0; k < 64; ++k) wcol[k] = W3[k * 128 + o];
  float bias = b3[o];
  int base = blockIdx.x * D3_NPB;
  float acc = 0.f;
  int curg = -1;
#pragma unroll 1
  for (int c0 = 0; c0 < D3_NPB; c0 += D3_CH) {
    __syncthreads();
#pragma unroll
    for (int r = 0; r < (D3_CH * 16) / 256; ++r) {
      int idx = r * 256 + t;  // float4 index within chunk
      int node = base + c0 + (idx >> 4);
      float4 v = make_float4(0.f, 0.f, 0.f, 0.f);
      if (node < NN) v = ((const float4*)(a + (size_t)node * 64))[idx & 15];
      ((float4*)sa)[idx] = v;
    }
    __syncthreads();
#pragma unroll 1
    for (int j = 0; j < D3_CH / 2; ++j) {
      int local = half * (D3_CH / 2) + j;
      int n = base + c0 + local;
      if (n >= NN) break;
      const float* row = sa + local * 64;
      float v = bias;
#pragma unroll
      for (int q = 0; q < 16; ++q) {
        float4 av = ((const float4*)row)[q];
        v += av.x * wcol[4 * q] + av.y * wcol[4 * q + 1] + av.z * wcol[4 * q + 2] +
             av.w * wcol[4 * q + 3];
      }
      int g = batch[n];
      if (g != curg) {
        if (curg >= 0) atomicAdd(&gsum[curg * 128 + o], acc);
        curg = g;
        acc = 0.f;
      }
      acc += fmaxf(v, 0.f);
    }
  }
  if (curg >= 0) atomicAdd(&gsum[curg * 128 + o], acc);
}

// one wave per graph: logits = (gsum/cnt) @ Wl + bl; log_softmax over 16 classes
__global__ void k_head(const float* __restrict__ gsum, const int* __restrict__ gstart,
                       const float* __restrict__ Wl, const float* __restrict__ bl,
                       float* __restrict__ out) {
  int wave = threadIdx.x >> 6, lane = threadIdx.x & 63;
  int g = blockIdx.x * 4 + wave;
  if (g >= NG) return;
  int c = lane & 15, part = lane >> 4;
  float acc = 0.f;
#pragma unroll
  for (int kk = 0; kk < 32; ++kk) {
    int k = part * 32 + kk;
    acc += gsum[g * 128 + k] * Wl[k * NC + c];
  }
  acc += __shfl_xor(acc, 16);
  acc += __shfl_xor(acc, 32);
  int cnt = gstart[g + 1] - gstart[g];
  float inv = 1.0f / (float)max(cnt, 1);
  float logit = acc * inv + bl[c];
  float m = logit;
#pragma unroll
  for (int d = 1; d < 16; d <<= 1) m = fmaxf(m, __shfl_xor(m, d));
  float ex = expf(logit - m), s = ex;
#pragma unroll
  for (int d = 1; d < 16; d <<= 1) s += __shfl_xor(s, d);
  if (lane < 16) out[g * NC + lane] = logit - m - logf(s);
}

extern "C" void kernel_launch(void* const* d_in, const int* in_sizes, int n_in,
                              void* d_out, int out_size, void* d_ws, size_t ws_size,
                              hipStream_t stream) {
  const float* x = (const float*)d_in[0];
  const int* ei = (const int*)d_in[1];
  const int* batch = (const int*)d_in[2];
  const float* W1 = (const float*)d_in[3];
  const float* b1 = (const float*)d_in[4];
  const float* W2 = (const float*)d_in[5];
  const float* b2 = (const float*)d_in[6];
  const float* W3 = (const float*)d_in[7];
  const float* b3 = (const float*)d_in[8];
  const float* Wl = (const float*)d_in[9];
  const float* bl = (const float*)d_in[10];
  const int* src = ei;
  const int* dst = ei + NE;

  // workspace layout (zero range = cnt..gsum, contiguous)
  int* cnt = (int*)d_ws;                   // NN*HC
  int* fillc = cnt + NN * HC;              // NN*HC
  float* gsum = (float*)(fillc + NN * HC); // NG*128
  int* count = (int*)(gsum + NG * 128);    // NN
  int* offs = count + NN;                  // NN
  int* gstart = offs + NN;                 // NG+2
  int* bsum = gstart + NG + 2;             // 1024
  int* bpref = bsum + 1024;                // 1024
  float* dinv = (float*)(bpref + 1024);    // NN
  int2* csr = (int2*)(dinv + NN);          // NE int2
  float* bufA = (float*)(csr + NE);        // NN*64
  float* bufH = bufA + (size_t)NN * 64;    // NN*64

  const int B = 256;
  const int NB_SCAN = cdiv(NN, 256);  // 391
  const int n_zero_elems = 2 * NN * HC + NG * 128;

  // CSR build + norms + graph bounds
  k_zero_i<<<cdiv(n_zero_elems, B), B, 0, stream>>>(cnt, n_zero_elems);
  k_hist8<<<cdiv(NE, B), B, 0, stream>>>(dst, cnt);
  k_bounds<<<cdiv(NN + 1, B), B, 0, stream>>>(batch, gstart);
  k_reduce<<<cdiv(NN, B), B, 0, stream>>>(cnt, count, dinv);
  k_scan1<<<NB_SCAN, 256, 0, stream>>>(count, offs, bsum, NN);
  k_scan2<<<1, 512, 0, stream>>>(bsum, bpref, NB_SCAN);
  k_scan3<<<cdiv(NN, B), B, 0, stream>>>(offs, bpref, NN);
  k_fill<<<cdiv(NE, B), B, 0, stream>>>(src, dst, offs, cnt, fillc, dinv, csr);

  // layer 1: agg(x,13) -> dense 13->16
  k_agg<13, 16><<<cdiv(NN, 16), B, 0, stream>>>(x, csr, offs, count, dinv, bufA);
  k_dense_relu<13, 16><<<cdiv((long long)NN * 16, B), B, 0, stream>>>(bufA, W1, b1, bufH, NN);
  // layer 2: agg(h1,16) -> dense 16->64
  k_agg<16, 16><<<cdiv(NN, 16), B, 0, stream>>>(bufH, csr, offs, count, dinv, bufA);
  k_dense_relu<16, 64><<<cdiv((long long)NN * 64, B), B, 0, stream>>>(bufA, W2, b2, bufH, NN);
  // layer 3: agg(h2,64) -> fused dense(64->128)+relu+pool
  k_agg<64, 64><<<cdiv(NN, 4), B, 0, stream>>>(bufH, csr, offs, count, dinv, bufA);
  k_dense3_pool3<<<cdiv(NN, D3_NPB), 256, 0, stream>>>(bufA, W3, b3, batch, gsum);

  // head
  k_head<<<NG / 4, B, 0, stream>>>(gsum, gstart, Wl, bl, (float*)d_out);
}